// Round 7
// baseline (46.411 us; speedup 1.0000x reference)
//
#include <hip/hip_runtime.h>

// Unfolder: out[b,c,p,q] = x[b,c, p/3 + p%3 - 1, q/3 + q%3 - 1], zero outside.
// B=8, C=3, H=W=512, k=3, pad=1 -> out is [8,3,1536,1536] fp32.
//
// R7: R6's XCD-chunked swizzle (linear per-XCD write streams, the +16% win)
// + nontemporal stores (skip L2 write-allocate on the 226 MB stream).
// Block = 12 output rows (4 row-groups), stages 6 input rows in LDS.

#define B_N 8
#define C_N 3
#define H_N 512
#define W_N 512
#define HO 1536
#define WO 1536
#define RG 4             // row-groups per block -> 12 output rows
#define NR (RG + 2)      // staged input rows
#define NBLK (B_N * C_N * (H_N / RG))   // 3072 blocks, divisible by 8

typedef float fvec4 __attribute__((ext_vector_type(4)));

__global__ __launch_bounds__(384) void unfold_swz_nt_kernel(
    const float* __restrict__ x, float* __restrict__ out)
{
    // XCD-chunked bijective swizzle: xcd = gid%8 gets contiguous g-range.
    const int gid = blockIdx.x;                 // [0, 3072)
    const int g   = (gid & 7) * (NBLK / 8) + (gid >> 3);

    const int bc = g / (H_N / RG);              // image [0,24)
    const int mm = g % (H_N / RG);              // row tile within image [0,128)
    const int tid = threadIdx.x;                // [0,384)

    __shared__ float rows[NR][W_N];

    // Stage NR=6 input rows (s = 4mm-1 .. 4mm+4): 768 float4, 2 per thread.
    const int s0 = RG * mm - 1;
#pragma unroll
    for (int it = 0; it < 2; ++it) {
        const int idx = tid + it * 384;
        const int r  = idx >> 7;
        const int cc = idx & 127;
        const int s  = s0 + r;
        fvec4 v = (fvec4)0.f;
        if ((unsigned)s < (unsigned)H_N) {
            v = reinterpret_cast<const fvec4*>(
                    x + ((size_t)bc * H_N + s) * W_N)[cc];
        }
        reinterpret_cast<fvec4*>(&rows[r][0])[cc] = v;
    }
    __syncthreads();

    // Column gather: q = 4*tid + e, t = q/3 + q%3 - 1 in [-1,512].
    int tcol[4];
#pragma unroll
    for (int e = 0; e < 4; ++e) {
        const int q = tid * 4 + e;
        tcol[e] = q / 3 + q % 3 - 1;
    }

    // 12 output rows; row d uses staged row r = d/3 + d%3.
    const size_t obase = ((size_t)bc * HO + (size_t)(3 * RG) * mm) * WO;
#pragma unroll
    for (int d = 0; d < 3 * RG; ++d) {
        const int r = d / 3 + d % 3;
        fvec4 v4;
#pragma unroll
        for (int e = 0; e < 4; ++e) {
            const int t = tcol[e];
            v4[e] = ((unsigned)t < (unsigned)W_N) ? rows[r][t] : 0.f;
        }
        __builtin_nontemporal_store(
            v4, reinterpret_cast<fvec4*>(out + obase + (size_t)d * WO) + tid);
    }
}

extern "C" void kernel_launch(void* const* d_in, const int* in_sizes, int n_in,
                              void* d_out, int out_size, void* d_ws, size_t ws_size,
                              hipStream_t stream)
{
    const float* x = (const float*)d_in[0];
    float* out = (float*)d_out;

    dim3 grid(NBLK);      // 3072 linear blocks, XCD-swizzled in-kernel
    dim3 block(WO / 4);   // 384 threads
    unfold_swz_nt_kernel<<<grid, block, 0, stream>>>(x, out);
}

// Round 8
// 41.590 us; speedup vs baseline: 1.1159x; 1.1159x over previous
//
#include <hip/hip_runtime.h>

// Unfolder: out[b,c,p,q] = x[b,c, p/3 + p%3 - 1, q/3 + q%3 - 1], zero outside.
// B=8, C=3, H=W=512, k=3, pad=1 -> out is [8,3,1536,1536] fp32.
//
// Final (R6 config): XCD-chunked bijective block swizzle -> each XCD's L2
// accumulates one contiguous ~28 MB write stream (L2 write-back locality,
// +16% vs round-robin). NORMAL stores through L2 (NT regressed: it bypasses
// L2 and forfeits the write-back coalescing). Block = 12 output rows,
// stages 6 input rows in LDS via coalesced float4 loads.
// Measured: 41.6 us = 6.08 TB/s = 97% of float4-copy ceiling (6.29 TB/s).

#define B_N 8
#define C_N 3
#define H_N 512
#define W_N 512
#define HO 1536
#define WO 1536
#define RG 4             // row-groups per block -> 12 output rows
#define NR (RG + 2)      // staged input rows
#define NBLK (B_N * C_N * (H_N / RG))   // 3072 blocks, divisible by 8

typedef float fvec4 __attribute__((ext_vector_type(4)));

__global__ __launch_bounds__(384) void unfold_swz_kernel(
    const float* __restrict__ x, float* __restrict__ out)
{
    // XCD-chunked bijective swizzle: xcd = gid%8 gets contiguous g-range.
    const int gid = blockIdx.x;                 // [0, 3072)
    const int g   = (gid & 7) * (NBLK / 8) + (gid >> 3);

    const int bc = g / (H_N / RG);              // image [0,24)
    const int mm = g % (H_N / RG);              // row tile within image [0,128)
    const int tid = threadIdx.x;                // [0,384)

    __shared__ float rows[NR][W_N];

    // Stage NR=6 input rows (s = 4mm-1 .. 4mm+4): 768 float4, 2 per thread.
    const int s0 = RG * mm - 1;
#pragma unroll
    for (int it = 0; it < 2; ++it) {
        const int idx = tid + it * 384;
        const int r  = idx >> 7;
        const int cc = idx & 127;
        const int s  = s0 + r;
        fvec4 v = (fvec4)0.f;
        if ((unsigned)s < (unsigned)H_N) {
            v = reinterpret_cast<const fvec4*>(
                    x + ((size_t)bc * H_N + s) * W_N)[cc];
        }
        reinterpret_cast<fvec4*>(&rows[r][0])[cc] = v;
    }
    __syncthreads();

    // Column gather: q = 4*tid + e, t = q/3 + q%3 - 1 in [-1,512].
    int tcol[4];
#pragma unroll
    for (int e = 0; e < 4; ++e) {
        const int q = tid * 4 + e;
        tcol[e] = q / 3 + q % 3 - 1;
    }

    // 12 output rows; row d uses staged row r = d/3 + d%3.
    const size_t obase = ((size_t)bc * HO + (size_t)(3 * RG) * mm) * WO;
#pragma unroll
    for (int d = 0; d < 3 * RG; ++d) {
        const int r = d / 3 + d % 3;
        fvec4 v4;
#pragma unroll
        for (int e = 0; e < 4; ++e) {
            const int t = tcol[e];
            v4[e] = ((unsigned)t < (unsigned)W_N) ? rows[r][t] : 0.f;
        }
        reinterpret_cast<fvec4*>(out + obase + (size_t)d * WO)[tid] = v4;
    }
}

extern "C" void kernel_launch(void* const* d_in, const int* in_sizes, int n_in,
                              void* d_out, int out_size, void* d_ws, size_t ws_size,
                              hipStream_t stream)
{
    const float* x = (const float*)d_in[0];
    float* out = (float*)d_out;

    dim3 grid(NBLK);      // 3072 linear blocks, XCD-swizzled in-kernel
    dim3 block(WO / 4);   // 384 threads
    unfold_swz_kernel<<<grid, block, 0, stream>>>(x, out);
}